// Round 8
// baseline (145.483 us; speedup 1.0000x reference)
//
#include <hip/hip_runtime.h>
#include <math.h>

#define NO 10
#define NFEAT 68
#define HR 5            // rows per half
#define MAXNR 2048      // max N*NO
#define MAXDEG 1536     // max incident entries per atom
#define MAXLIST 1024    // (fallback kernel)

// Packed feature table: bits 0-3 = oi, bits 4-7 = oj, bit 8 = (fac==0.5)
__device__ const unsigned short g_pk[NFEAT] = {
    0x100, 0x010, 0x020, 0x030, 0x040, 0x050, 0x060, 0x070, 0x080, 0x090,
    0x111, 0x021, 0x031, 0x041, 0x051, 0x061, 0x071, 0x081, 0x091,
    0x122, 0x132, 0x142, 0x123, 0x133, 0x143, 0x124, 0x134, 0x144,
    0x052, 0x062, 0x072, 0x082, 0x092,
    0x053, 0x063, 0x073, 0x083, 0x093,
    0x054, 0x064, 0x074, 0x084, 0x094,
    0x155, 0x165, 0x175, 0x185, 0x195,
    0x156, 0x166, 0x176, 0x186, 0x196,
    0x157, 0x167, 0x177, 0x187, 0x197,
    0x158, 0x168, 0x178, 0x188, 0x198,
    0x159, 0x169, 0x179, 0x189, 0x199
};

// ---------------- precompute kernels ----------------

// K0: sin table sins[k*E+e] = sin(2pi k.R_e); zero per-atom counters.
__global__ void k0_init(const float* __restrict__ ecs, const float* __restrict__ kp,
                        float* __restrict__ sins, int* __restrict__ d0,
                        int* __restrict__ d1, int* __restrict__ entcur,
                        int E, int N, int NK) {
    int idx = blockIdx.x * blockDim.x + threadIdx.x;
    int stride = gridDim.x * blockDim.x;
    const float TWO_PI = 6.283185307179586f;
    for (int x = idx; x < NK * E; x += stride) {
        int k = x / E, e = x - k * E;
        float th = TWO_PI * (kp[k*3]*ecs[e*3] + kp[k*3+1]*ecs[e*3+1] + kp[k*3+2]*ecs[e*3+2]);
        sins[x] = sinf(th);
    }
    for (int x = idx; x < N; x += stride) { d0[x] = 0; d1[x] = 0; entcur[x] = 0; }
}

// K1: per-atom entry counts (dir0 = atom is src, dir1 = atom is dst).
__global__ void k1_count(const int* __restrict__ eidx, int* __restrict__ d0,
                         int* __restrict__ d1, int E) {
    int e = blockIdx.x * blockDim.x + threadIdx.x;
    if (e < E) { atomicAdd(&d0[eidx[e]], 1); atomicAdd(&d1[eidx[E + e]], 1); }
}

// K2: serial prefix sum over 2N buckets (h0 size = 43*d0+18*d1, h1 = 25*d0+50*d1).
__global__ void k2_scan(const int* __restrict__ d0, const int* __restrict__ d1,
                        int* __restrict__ boff, int* __restrict__ bcnt,
                        int* __restrict__ bcur, int N) {
    if (blockIdx.x == 0 && threadIdx.x == 0) {
        int run = 0;
        for (int i = 0; i < N; ++i) {
            int s0 = 43 * d0[i] + 18 * d1[i];
            int s1 = 25 * d0[i] + 50 * d1[i];
            boff[i*2] = run; bcnt[i*2] = s0; bcur[i*2] = run; run += s0;
            boff[i*2+1] = run; bcnt[i*2+1] = s1; bcur[i*2+1] = run; run += s1;
        }
    }
}

// K3: emit CSR entries + bucketed items. Item = (val = fac*ef, packed col|rr|t).
__global__ void k3_emit(const float* __restrict__ ef, const int* __restrict__ eidx,
                        int* __restrict__ ents, int* __restrict__ entcur,
                        int* __restrict__ bcur, float2* __restrict__ items, int E) {
    int idx = blockIdx.x * blockDim.x + threadIdx.x;
    if (idx >= 2 * E) return;
    int dir = idx >= E;
    int e   = dir ? idx - E : idx;
    int i   = dir ? eidx[E + e] : eidx[e];
    int j   = dir ? eidx[e]     : eidx[E + e];
    int t = atomicAdd(&entcur[i], 1);
    bool drop = (t >= MAXDEG);
    if (!drop) ents[i * MAXDEG + t] = e;
    int tt = drop ? 0 : t;
    int n0 = dir ? 18 : 43;
    int b0 = atomicAdd(&bcur[i*2],     n0);
    int b1 = atomicAdd(&bcur[i*2 + 1], NFEAT - n0);
    int c0 = 0, c1 = 0;
    for (int f = 0; f < NFEAT; ++f) {
        unsigned pk = g_pk[f];
        int oi = pk & 15, oj = (pk >> 4) & 15;
        int row    = dir ? oj : oi;
        int colorb = dir ? oi : oj;
        float val  = drop ? 0.f : ((pk & 256) ? 0.5f : 1.0f) * ef[e * NFEAT + f];
        int h  = row >= HR;
        int rr = row - h * HR;
        unsigned packed = (unsigned)(j * NO + colorb) | ((unsigned)rr << 11) | ((unsigned)tt << 14);
        float2 it; it.x = val; it.y = __uint_as_float(packed);
        int pos = h ? (b1 + c1++) : (b0 + c0++);
        items[pos] = it;
    }
}

// K4: main. One wg per (atom i, k, d, row-half h): coef -> zero -> stream items -> store.
__global__ __launch_bounds__(512)
void k4_main(const float* __restrict__ nf, const float* __restrict__ ev,
             const float* __restrict__ sins, const int* __restrict__ ents,
             const int* __restrict__ entcnt, const int* __restrict__ boff,
             const int* __restrict__ bcnt, const float2* __restrict__ items,
             float* __restrict__ out, int E, int N, int NK, size_t lim) {
    __shared__ float acc[HR * MAXNR];   // 40 KB
    __shared__ float coef[MAXDEG];      // 6 KB
    const int i = blockIdx.x, k = blockIdx.y;
    const int d = blockIdx.z >> 1, h = blockIdx.z & 1;
    const int tid = threadIdx.x, nthr = blockDim.x;
    const int NR = N * NO;
    if (NR > MAXNR) return;

    const int deg = min(entcnt[i], MAXDEG);
    for (int t = tid; t < deg; t += nthr) {
        int e = ents[i * MAXDEG + t];
        coef[t] = -ev[e * 3 + d] * sins[k * E + e];
    }
    {
        float4* a4 = (float4*)acc;
        int nz = (HR * NR) >> 2;
        float4 z = make_float4(0.f, 0.f, 0.f, 0.f);
        for (int x = tid; x < nz; x += nthr) a4[x] = z;
    }
    __syncthreads();

    const int base = boff[i*2 + h], cnt = bcnt[i*2 + h];
    for (int x = tid; x < cnt; x += nthr) {
        float2 it = items[base + x];
        unsigned p = __float_as_uint(it.y);
        int col = p & 2047, rr = (p >> 11) & 7, t = p >> 14;
        atomicAdd(&acc[rr * NR + col], it.x * coef[t]);
    }
    const int r0 = h * HR;
    for (int f = tid; f < NFEAT; f += nthr) {
        unsigned pk = g_pk[f];
        int oi = pk & 15, oj = (pk >> 4) & 15;
        float v = ((pk & 256) ? 0.5f : 1.0f) * nf[i * NFEAT + f];
        int ra = oi - r0, rb = oj - r0;
        if ((unsigned)ra < HR) atomicAdd(&acc[ra * NR + i * NO + oj], v);
        if ((unsigned)rb < HR) atomicAdd(&acc[rb * NR + i * NO + oi], v);
    }
    __syncthreads();

    size_t obase = ((size_t)(d * NK + k)) * NR * NR + (size_t)(i * NO + r0) * NR;
    int ntot = HR * NR;
    if ((NR & 3) == 0) {
        const float4* a4 = (const float4*)acc;
        int n4 = ntot >> 2;
        for (int x = tid; x < n4; x += nthr) {
            size_t idx = obase + (size_t)x * 4;
            if (idx + 3 < lim) *(float4*)(out + idx) = a4[x];
        }
    } else {
        for (int x = tid; x < ntot; x += nthr) {
            size_t idx = obase + x;
            if (idx < lim) out[idx] = acc[x];
        }
    }
}

// ---------------- fallback (round-7 kernel) if ws too small ----------------
__global__ __launch_bounds__(512)
void fused1d(const float* __restrict__ ef, const float* __restrict__ nf,
             const float* __restrict__ ev, const float* __restrict__ ecs,
             const float* __restrict__ kp, const int* __restrict__ eidx,
             float* __restrict__ out,
             int E, int N, int NK, size_t lim) {
    __shared__ float acc[HR * MAXNR];
    __shared__ float coef[MAXLIST];
    __shared__ int   elist[MAXLIST];
    __shared__ int   mcnt;
    const int i = blockIdx.x, k = blockIdx.y;
    const int d = blockIdx.z >> 1, h = blockIdx.z & 1;
    const int r0 = h * HR;
    const int tid = threadIdx.x, nthr = blockDim.x;
    const int NR = N * NO;
    if (NR > MAXNR) return;
    if (tid == 0) mcnt = 0;
    __syncthreads();
    for (int e = tid; e < E; e += nthr) {
        int s = eidx[e], t = eidx[E + e];
        if (s == i) { int p = atomicAdd(&mcnt, 1); if (p < MAXLIST) elist[p] = e * 2; }
        if (t == i) { int p = atomicAdd(&mcnt, 1); if (p < MAXLIST) elist[p] = e * 2 + 1; }
    }
    {
        float4* a4 = (float4*)acc;
        int nz = (HR * NR) >> 2;
        float4 z = make_float4(0.f, 0.f, 0.f, 0.f);
        for (int x = tid; x < nz; x += nthr) a4[x] = z;
    }
    __syncthreads();
    const int m = min(mcnt, MAXLIST);
    const float k0v = kp[k*3], k1v = kp[k*3+1], k2v = kp[k*3+2];
    const float TWO_PI = 6.283185307179586f;
    for (int t = tid; t < m; t += nthr) {
        int e = elist[t] >> 1;
        float th = TWO_PI * (k0v*ecs[e*3] + k1v*ecs[e*3+1] + k2v*ecs[e*3+2]);
        coef[t] = -ev[e*3 + d] * sinf(th);
    }
    __syncthreads();
    const int items = m * NFEAT;
    for (int it = tid; it < items; it += nthr) {
        int t = it / NFEAT, f = it - t * NFEAT;
        int ent = elist[t], e = ent >> 1, dir = ent & 1;
        unsigned pk = g_pk[f];
        int oi = pk & 15, oj = (pk >> 4) & 15;
        int row = dir ? oj : oi, rr = row - r0;
        if ((unsigned)rr < HR) {
            int col = dir ? oi : oj;
            int j = dir ? eidx[e] : eidx[E + e];
            float fac = (pk & 256) ? 0.5f : 1.0f;
            atomicAdd(&acc[rr * NR + j * NO + col], coef[t] * fac * ef[e * NFEAT + f]);
        }
    }
    for (int f = tid; f < NFEAT; f += nthr) {
        unsigned pk = g_pk[f];
        int oi = pk & 15, oj = (pk >> 4) & 15;
        float v = ((pk & 256) ? 0.5f : 1.0f) * nf[i * NFEAT + f];
        int ra = oi - r0, rb = oj - r0;
        if ((unsigned)ra < HR) atomicAdd(&acc[ra * NR + i * NO + oj], v);
        if ((unsigned)rb < HR) atomicAdd(&acc[rb * NR + i * NO + oi], v);
    }
    __syncthreads();
    size_t base = ((size_t)(d * NK + k)) * NR * NR + (size_t)(i * NO + r0) * NR;
    int ntot = HR * NR;
    if ((NR & 3) == 0) {
        const float4* a4 = (const float4*)acc;
        int n4 = ntot >> 2;
        for (int x = tid; x < n4; x += nthr) {
            size_t idx = base + (size_t)x * 4;
            if (idx + 3 < lim) *(float4*)(out + idx) = a4[x];
        }
    } else {
        for (int x = tid; x < ntot; x += nthr) {
            size_t idx = base + x;
            if (idx < lim) out[idx] = acc[x];
        }
    }
}

extern "C" void kernel_launch(void* const* d_in, const int* in_sizes, int n_in,
                              void* d_out, int out_size, void* d_ws, size_t ws_size,
                              hipStream_t stream) {
    const float* ef  = (const float*)d_in[0];
    const float* nf  = (const float*)d_in[1];
    const float* ev  = (const float*)d_in[2];
    const float* ecs = (const float*)d_in[3];
    const float* kp  = (const float*)d_in[4];
    const int*  eidx = (const int*)d_in[5];
    float* out = (float*)d_out;

    int E  = in_sizes[0] / NFEAT;
    int N  = in_sizes[1] / NFEAT;
    int NK = in_sizes[4] / 3;
    size_t lim = (size_t)out_size;

    // workspace layout
    size_t o = 0;
    auto alloc = [&](size_t bytes) { size_t r = o; o = (o + bytes + 255) & ~(size_t)255; return r; };
    size_t o_sins   = alloc((size_t)NK * E * 4);
    size_t o_ents   = alloc((size_t)N * MAXDEG * 4);
    size_t o_d0     = alloc((size_t)N * 4);
    size_t o_d1     = alloc((size_t)N * 4);
    size_t o_entcur = alloc((size_t)N * 4);
    size_t o_boff   = alloc((size_t)2 * N * 4);
    size_t o_bcnt   = alloc((size_t)2 * N * 4);
    size_t o_bcur   = alloc((size_t)2 * N * 4);
    size_t o_items  = alloc((size_t)2 * E * NFEAT * 8);
    size_t need = o;

    dim3 grid(N, NK, 6);
    if (ws_size < need || N * NO > MAXNR) {
        fused1d<<<grid, 512, 0, stream>>>(ef, nf, ev, ecs, kp, eidx, out, E, N, NK, lim);
        return;
    }

    char* ws = (char*)d_ws;
    float*  sins   = (float*)(ws + o_sins);
    int*    ents   = (int*)(ws + o_ents);
    int*    d0c    = (int*)(ws + o_d0);
    int*    d1c    = (int*)(ws + o_d1);
    int*    entcur = (int*)(ws + o_entcur);
    int*    boff   = (int*)(ws + o_boff);
    int*    bcnt   = (int*)(ws + o_bcnt);
    int*    bcur   = (int*)(ws + o_bcur);
    float2* items  = (float2*)(ws + o_items);

    k0_init<<<96, 256, 0, stream>>>(ecs, kp, sins, d0c, d1c, entcur, E, N, NK);
    k1_count<<<(E + 255) / 256, 256, 0, stream>>>(eidx, d0c, d1c, E);
    k2_scan<<<1, 64, 0, stream>>>(d0c, d1c, boff, bcnt, bcur, N);
    k3_emit<<<(2 * E + 255) / 256, 256, 0, stream>>>(ef, eidx, ents, entcur, bcur, items, E);
    k4_main<<<grid, 512, 0, stream>>>(nf, ev, sins, ents, entcur, boff, bcnt, items,
                                      out, E, N, NK, lim);
}